// Round 1
// baseline (519.777 us; speedup 1.0000x reference)
//
#include <hip/hip_runtime.h>
#include <math.h>

#define IN_F 64
#define HID 128
#define NCLS 10
#define LSM_BLOCKS 1024

// ---------- utility ----------
__global__ void k_zero_int(int* __restrict__ p, int n) {
    int i = blockIdx.x * blockDim.x + threadIdx.x;
    if (i < n) p[i] = 0;
}

// ---------- degree histogram over targets ----------
__global__ void k_hist(const int* __restrict__ col, int* __restrict__ cnt, int E) {
    int i = blockIdx.x * blockDim.x + threadIdx.x;
    if (i < E) atomicAdd(&cnt[col[i]], 1);
}

// ---------- 3-kernel exclusive scan (cnt -> rowptr), fused dis + pos init ----------
__global__ void k_blocksum(const int* __restrict__ cnt, int* __restrict__ bsum, int n) {
    __shared__ int s[256];
    int i = blockIdx.x * 256 + threadIdx.x;
    s[threadIdx.x] = (i < n) ? cnt[i] : 0;
    __syncthreads();
    for (int off = 128; off > 0; off >>= 1) {
        if (threadIdx.x < off) s[threadIdx.x] += s[threadIdx.x + off];
        __syncthreads();
    }
    if (threadIdx.x == 0) bsum[blockIdx.x] = s[0];
}

__global__ void k_scan_bsum(const int* __restrict__ bsum, int* __restrict__ boff, int nb,
                            int* __restrict__ rowptr, int n, int E) {
    __shared__ int s[512];
    int t = threadIdx.x;
    int v = (t < nb) ? bsum[t] : 0;
    s[t] = v;
    __syncthreads();
    for (int off = 1; off < 512; off <<= 1) {
        int tmp = (t >= off) ? s[t - off] : 0;
        __syncthreads();
        s[t] += tmp;
        __syncthreads();
    }
    if (t < nb) boff[t] = s[t] - v;  // exclusive
    if (t == 0) rowptr[n] = E;
}

__global__ void k_scan_final(const int* __restrict__ cnt, const int* __restrict__ boff,
                             int* __restrict__ rowptr, int* __restrict__ pos,
                             float* __restrict__ dis, int n) {
    __shared__ int s[256];
    int i = blockIdx.x * 256 + threadIdx.x;
    int v = (i < n) ? cnt[i] : 0;
    s[threadIdx.x] = v;
    __syncthreads();
    for (int off = 1; off < 256; off <<= 1) {
        int tmp = (threadIdx.x >= off) ? s[threadIdx.x - off] : 0;
        __syncthreads();
        s[threadIdx.x] += tmp;
        __syncthreads();
    }
    if (i < n) {
        int rp = boff[blockIdx.x] + s[threadIdx.x] - v;  // exclusive
        rowptr[i] = rp;
        pos[i] = rp;                       // running cursor for k_fill
        dis[i] = rsqrtf(1.0f + (float)v);  // +1 self-loop
    }
}

// ---------- CSR fill: src list sorted by target (pos pre-seeded with rowptr) ----------
__global__ void k_fill(const int* __restrict__ row, const int* __restrict__ col,
                       int* __restrict__ pos, int* __restrict__ src, int E) {
    int e = blockIdx.x * blockDim.x + threadIdx.x;
    if (e >= E) return;
    int c = col[e];
    int p = atomicAdd(&pos[c], 1);
    src[p] = row[e];
}

// ---------- fused: gather1(+dis) + GEMM1 + bias + relu + W2 projection ----------
// one wave per node; 4 edge slots x 16 lanes x float4; unroll x4 => 16 rows in flight
// epilogue: h (128) kept in regs (h0,h1 per lane), dot with W2 via butterfly reduce,
// writes padded 16-float h2p row. No block barrier (wave-local LDS sync only).
__global__ __launch_bounds__(256) void k_l1(const float* __restrict__ x,
                                            const int* __restrict__ src,
                                            const int* __restrict__ rowptr,
                                            const float* __restrict__ dis,
                                            const float* __restrict__ W1,
                                            const float* __restrict__ b1,
                                            const float* __restrict__ W2,
                                            float* __restrict__ h2p, int n) {
    __shared__ float hacc[4][64];
    int w = threadIdx.x >> 6, lane = threadIdx.x & 63;
    int q = lane >> 4;   // edge slot 0..3
    int f4 = lane & 15;  // float4 chunk within 64-float row
    int i = blockIdx.x * 4 + w;
    if (i >= n) return;  // wave-uniform; no barriers below => safe

    float d = dis[i];
    float4 acc = make_float4(0.f, 0.f, 0.f, 0.f);
    if (q == 0) {  // self-loop: d * x_i (counted once)
        float4 v = ((const float4*)(x + (size_t)i * IN_F))[f4];
        acc.x = v.x * d; acc.y = v.y * d; acc.z = v.z * d; acc.w = v.w * d;
    }
    int end = rowptr[i + 1];
    int e = rowptr[i] + q;
    for (; e + 12 < end; e += 16) {
        int s0 = src[e], s1 = src[e + 4], s2 = src[e + 8], s3 = src[e + 12];
        float d0 = dis[s0], d1 = dis[s1], d2 = dis[s2], d3 = dis[s3];
        float4 v0 = ((const float4*)(x + (size_t)s0 * IN_F))[f4];
        float4 v1 = ((const float4*)(x + (size_t)s1 * IN_F))[f4];
        float4 v2 = ((const float4*)(x + (size_t)s2 * IN_F))[f4];
        float4 v3 = ((const float4*)(x + (size_t)s3 * IN_F))[f4];
        acc.x = fmaf(v0.x, d0, acc.x); acc.y = fmaf(v0.y, d0, acc.y);
        acc.z = fmaf(v0.z, d0, acc.z); acc.w = fmaf(v0.w, d0, acc.w);
        acc.x = fmaf(v1.x, d1, acc.x); acc.y = fmaf(v1.y, d1, acc.y);
        acc.z = fmaf(v1.z, d1, acc.z); acc.w = fmaf(v1.w, d1, acc.w);
        acc.x = fmaf(v2.x, d2, acc.x); acc.y = fmaf(v2.y, d2, acc.y);
        acc.z = fmaf(v2.z, d2, acc.z); acc.w = fmaf(v2.w, d2, acc.w);
        acc.x = fmaf(v3.x, d3, acc.x); acc.y = fmaf(v3.y, d3, acc.y);
        acc.z = fmaf(v3.z, d3, acc.z); acc.w = fmaf(v3.w, d3, acc.w);
    }
    for (; e + 4 < end; e += 8) {
        int s0 = src[e], s1 = src[e + 4];
        float d0 = dis[s0], d1 = dis[s1];
        float4 v0 = ((const float4*)(x + (size_t)s0 * IN_F))[f4];
        float4 v1 = ((const float4*)(x + (size_t)s1 * IN_F))[f4];
        acc.x = fmaf(v0.x, d0, acc.x); acc.y = fmaf(v0.y, d0, acc.y);
        acc.z = fmaf(v0.z, d0, acc.z); acc.w = fmaf(v0.w, d0, acc.w);
        acc.x = fmaf(v1.x, d1, acc.x); acc.y = fmaf(v1.y, d1, acc.y);
        acc.z = fmaf(v1.z, d1, acc.z); acc.w = fmaf(v1.w, d1, acc.w);
    }
    if (e < end) {
        int s0 = src[e];
        float d0 = dis[s0];
        float4 v0 = ((const float4*)(x + (size_t)s0 * IN_F))[f4];
        acc.x = fmaf(v0.x, d0, acc.x); acc.y = fmaf(v0.y, d0, acc.y);
        acc.z = fmaf(v0.z, d0, acc.z); acc.w = fmaf(v0.w, d0, acc.w);
    }
    // combine the 4 edge slots
    acc.x += __shfl_xor(acc.x, 16); acc.y += __shfl_xor(acc.y, 16);
    acc.z += __shfl_xor(acc.z, 16); acc.w += __shfl_xor(acc.w, 16);
    acc.x += __shfl_xor(acc.x, 32); acc.y += __shfl_xor(acc.y, 32);
    acc.z += __shfl_xor(acc.z, 32); acc.w += __shfl_xor(acc.w, 32);
    if (q == 0) {
        acc.x *= d; acc.y *= d; acc.z *= d; acc.w *= d;
        ((float4*)hacc[w])[f4] = acc;
    }
    // wave-local LDS visibility: writer lanes and readers are the same wave
    asm volatile("s_waitcnt lgkmcnt(0)" ::: "memory");

    float h0 = b1[lane], h1 = b1[lane + 64];
#pragma unroll
    for (int k4 = 0; k4 < 16; ++k4) {
        float4 a = ((const float4*)hacc[w])[k4];  // LDS broadcast
        const float* wp = W1 + (k4 * 4) * HID + lane;
        h0 = fmaf(a.x, wp[0 * HID], h0);      h1 = fmaf(a.x, wp[0 * HID + 64], h1);
        h0 = fmaf(a.y, wp[1 * HID], h0);      h1 = fmaf(a.y, wp[1 * HID + 64], h1);
        h0 = fmaf(a.z, wp[2 * HID], h0);      h1 = fmaf(a.z, wp[2 * HID + 64], h1);
        h0 = fmaf(a.w, wp[3 * HID], h0);      h1 = fmaf(a.w, wp[3 * HID + 64], h1);
    }
    h0 = fmaxf(h0, 0.f);
    h1 = fmaxf(h1, 0.f);

    // W2 projection: lane owns h-features {lane, lane+64}
    const float* w2a = W2 + lane * NCLS;
    const float* w2b = W2 + (lane + 64) * NCLS;
    float p[NCLS];
#pragma unroll
    for (int c = 0; c < NCLS; ++c) p[c] = fmaf(h0, w2a[c], h1 * w2b[c]);
#pragma unroll
    for (int c = 0; c < NCLS; ++c) {
        float v = p[c];
        v += __shfl_xor(v, 1);  v += __shfl_xor(v, 2);  v += __shfl_xor(v, 4);
        v += __shfl_xor(v, 8);  v += __shfl_xor(v, 16); v += __shfl_xor(v, 32);
        p[c] = v;
    }
    if (lane == 0) {  // padded 16-float row (zeros in 10..15)
        float4* o = (float4*)(h2p + (size_t)i * 16);
        o[0] = make_float4(d * p[0], d * p[1], d * p[2], d * p[3]);
        o[1] = make_float4(d * p[4], d * p[5], d * p[6], d * p[7]);
        o[2] = make_float4(d * p[8], d * p[9], 0.f, 0.f);
        o[3] = make_float4(0.f, 0.f, 0.f, 0.f);
    }
}

// ---------- fused gather2 + b2 + log-softmax + per-block partial reduce ----------
// wave per node (grid-stride); 4 slots x 16 lanes; rows are padded 64B => coalesced
__global__ __launch_bounds__(256) void k_lsm2(const float* __restrict__ h2p,
                                              const int* __restrict__ src,
                                              const int* __restrict__ rowptr,
                                              const float* __restrict__ dis,
                                              const float* __restrict__ b2,
                                              float* __restrict__ partial, int n) {
    __shared__ float sred[4][16];
    int w = threadIdx.x >> 6, lane = threadIdx.x & 63;
    int q = lane >> 4, c = lane & 15;
    int gw = blockIdx.x * 4 + w;
    int nw = gridDim.x * 4;
    float b2c = (c < NCLS) ? b2[c] : 0.f;
    float bsum = 0.f;
    for (int i = gw; i < n; i += nw) {
        int beg = rowptr[i], end = rowptr[i + 1];
        float acc = (q == 0) ? h2p[(size_t)i * 16 + c] : 0.f;  // self
        int e = beg + q;
        for (; e + 12 < end; e += 16) {
            int s0 = src[e], s1 = src[e + 4], s2 = src[e + 8], s3 = src[e + 12];
            float v0 = h2p[(size_t)s0 * 16 + c];
            float v1 = h2p[(size_t)s1 * 16 + c];
            float v2 = h2p[(size_t)s2 * 16 + c];
            float v3 = h2p[(size_t)s3 * 16 + c];
            acc += (v0 + v1) + (v2 + v3);
        }
        for (; e + 4 < end; e += 8) {
            int s0 = src[e], s1 = src[e + 4];
            acc += h2p[(size_t)s0 * 16 + c] + h2p[(size_t)s1 * 16 + c];
        }
        if (e < end) acc += h2p[(size_t)src[e] * 16 + c];
        // combine slots (all lanes end with the full sum)
        acc += __shfl_xor(acc, 16);
        acc += __shfl_xor(acc, 32);
        float vv = b2c + dis[i] * acc;
        // softmax over c=0..9 within each 16-lane group
        float m = (c < NCLS) ? vv : -1e30f;
        m = fmaxf(m, __shfl_xor(m, 1));
        m = fmaxf(m, __shfl_xor(m, 2));
        m = fmaxf(m, __shfl_xor(m, 4));
        m = fmaxf(m, __shfl_xor(m, 8));
        float ex = (c < NCLS) ? __expf(vv - m) : 0.f;
        float se = ex;
        se += __shfl_xor(se, 1);
        se += __shfl_xor(se, 2);
        se += __shfl_xor(se, 4);
        se += __shfl_xor(se, 8);
        float lse = m + __logf(se);
        if (q == 0 && c < NCLS) bsum += vv - lse;
    }
    if (q == 0) sred[w][c] = bsum;  // c>=10 lanes wrote 0
    __syncthreads();
    if (threadIdx.x < 16) {
        float t = sred[0][threadIdx.x] + sred[1][threadIdx.x] +
                  sred[2][threadIdx.x] + sred[3][threadIdx.x];
        partial[blockIdx.x * 16 + threadIdx.x] = t;
    }
}

// ---------- final reduction of per-block partials ----------
__global__ void k_final(const float* __restrict__ partial, float* __restrict__ out,
                        int nb16, float inv_n) {
    __shared__ float sred[256];
    float s = 0.f;
    for (int j = threadIdx.x; j < nb16; j += 256) s += partial[j];  // j&15 constant per thread
    sred[threadIdx.x] = s;
    __syncthreads();
    if (threadIdx.x < 16) {
        float t = 0.f;
        for (int r = threadIdx.x; r < 256; r += 16) t += sred[r];
        if (threadIdx.x < NCLS) out[threadIdx.x] = t * inv_n;
    }
}

extern "C" void kernel_launch(void* const* d_in, const int* in_sizes, int n_in,
                              void* d_out, int out_size, void* d_ws, size_t ws_size,
                              hipStream_t stream) {
    const float* x = (const float*)d_in[0];
    const int* eidx = (const int*)d_in[1];
    const float* W1 = (const float*)d_in[2];
    const float* b1 = (const float*)d_in[3];
    const float* W2 = (const float*)d_in[4];
    const float* b2 = (const float*)d_in[5];
    float* out = (float*)d_out;

    const int N = in_sizes[0] / IN_F;  // 100000
    const int E = in_sizes[1] / 2;     // 1600000
    const int* row = eidx;             // sources
    const int* col = eidx + E;         // targets

    const int NB = (N + 255) / 256;  // scan blocks (391 <= 512)

    // workspace layout (4-byte words, 1024-word aligned)
    size_t o = 0;
    auto alloc = [&](size_t words) {
        size_t r = o;
        o += (words + 1023) & ~(size_t)1023;
        return r;
    };
    float* ws = (float*)d_ws;
    float* dis = ws + alloc(N);
    float* h2p = ws + alloc((size_t)N * 16);
    float* partial = ws + alloc(LSM_BLOCKS * 16);
    int* src = (int*)(ws + alloc(E));
    int* rowptr = (int*)(ws + alloc(N + 1));
    int* cnt = (int*)(ws + alloc(N));
    int* pos = (int*)(ws + alloc(N));
    int* bsum = (int*)(ws + alloc(1024));
    int* boff = (int*)(ws + alloc(1024));

    const int B = 256;

    // ---- CSR build + degrees (dis, pos fused into scan) ----
    k_zero_int<<<(N + B - 1) / B, B, 0, stream>>>(cnt, N);
    k_hist<<<(E + B - 1) / B, B, 0, stream>>>(col, cnt, E);
    k_blocksum<<<NB, 256, 0, stream>>>(cnt, bsum, N);
    k_scan_bsum<<<1, 512, 0, stream>>>(bsum, boff, NB, rowptr, N, E);
    k_scan_final<<<NB, 256, 0, stream>>>(cnt, boff, rowptr, pos, dis, N);
    k_fill<<<(E + B - 1) / B, B, 0, stream>>>(row, col, pos, src, E);

    // ---- layer 1 + relu + W2 projection, all fused ----
    k_l1<<<(N + 3) / 4, 256, 0, stream>>>(x, src, rowptr, dis, W1, b1, W2, h2p, N);

    // ---- layer 2 aggregate + log-softmax + partial reduce ----
    k_lsm2<<<LSM_BLOCKS, 256, 0, stream>>>(h2p, src, rowptr, dis, b2, partial, N);
    k_final<<<1, 256, 0, stream>>>(partial, out, LSM_BLOCKS * 16, 1.0f / (float)N);
}

// Round 2
// 514.647 us; speedup vs baseline: 1.0100x; 1.0100x over previous
//
#include <hip/hip_runtime.h>
#include <math.h>

#define IN_F 64
#define HID 128
#define NCLS 10
#define LSM_BLOCKS 2048

// ---------- utility ----------
__global__ void k_zero_int(int* __restrict__ p, int n) {
    int i = blockIdx.x * blockDim.x + threadIdx.x;
    if (i < n) p[i] = 0;
}

// ---------- degree histogram over targets (4 edges/thread) ----------
__global__ void k_hist(const int* __restrict__ col, int* __restrict__ cnt, int E) {
    int i = blockIdx.x * blockDim.x + threadIdx.x;
    int e = i * 4;
    if (e + 3 < E) {
        int4 c = *(const int4*)(col + e);
        atomicAdd(&cnt[c.x], 1);
        atomicAdd(&cnt[c.y], 1);
        atomicAdd(&cnt[c.z], 1);
        atomicAdd(&cnt[c.w], 1);
    } else {
        for (int j = e; j < E; ++j) atomicAdd(&cnt[col[j]], 1);
    }
}

// ---------- 3-kernel exclusive scan (cnt -> rowptr), fused dis + pos init ----------
__global__ void k_blocksum(const int* __restrict__ cnt, int* __restrict__ bsum, int n) {
    __shared__ int s[256];
    int i = blockIdx.x * 256 + threadIdx.x;
    s[threadIdx.x] = (i < n) ? cnt[i] : 0;
    __syncthreads();
    for (int off = 128; off > 0; off >>= 1) {
        if (threadIdx.x < off) s[threadIdx.x] += s[threadIdx.x + off];
        __syncthreads();
    }
    if (threadIdx.x == 0) bsum[blockIdx.x] = s[0];
}

__global__ void k_scan_bsum(const int* __restrict__ bsum, int* __restrict__ boff, int nb,
                            int* __restrict__ rowptr, int n, int E) {
    __shared__ int s[512];
    int t = threadIdx.x;
    int v = (t < nb) ? bsum[t] : 0;
    s[t] = v;
    __syncthreads();
    for (int off = 1; off < 512; off <<= 1) {
        int tmp = (t >= off) ? s[t - off] : 0;
        __syncthreads();
        s[t] += tmp;
        __syncthreads();
    }
    if (t < nb) boff[t] = s[t] - v;  // exclusive
    if (t == 0) rowptr[n] = E;
}

__global__ void k_scan_final(const int* __restrict__ cnt, const int* __restrict__ boff,
                             int* __restrict__ rowptr, int* __restrict__ pos,
                             float* __restrict__ dis, int n) {
    __shared__ int s[256];
    int i = blockIdx.x * 256 + threadIdx.x;
    int v = (i < n) ? cnt[i] : 0;
    s[threadIdx.x] = v;
    __syncthreads();
    for (int off = 1; off < 256; off <<= 1) {
        int tmp = (threadIdx.x >= off) ? s[threadIdx.x - off] : 0;
        __syncthreads();
        s[threadIdx.x] += tmp;
        __syncthreads();
    }
    if (i < n) {
        int rp = boff[blockIdx.x] + s[threadIdx.x] - v;  // exclusive
        rowptr[i] = rp;
        pos[i] = rp;                       // running cursor for k_fill
        dis[i] = rsqrtf(1.0f + (float)v);  // +1 self-loop
    }
}

// ---------- CSR fill: src list sorted by target (pos pre-seeded with rowptr) ----------
__global__ void k_fill(const int* __restrict__ row, const int* __restrict__ col,
                       int* __restrict__ pos, int* __restrict__ src, int E) {
    int i = blockIdx.x * blockDim.x + threadIdx.x;
    int e = i * 4;
    if (e + 3 < E) {
        int4 c = *(const int4*)(col + e);
        int4 r = *(const int4*)(row + e);
        src[atomicAdd(&pos[c.x], 1)] = r.x;
        src[atomicAdd(&pos[c.y], 1)] = r.y;
        src[atomicAdd(&pos[c.z], 1)] = r.z;
        src[atomicAdd(&pos[c.w], 1)] = r.w;
    } else {
        for (int j = e; j < E; ++j) src[atomicAdd(&pos[col[j]], 1)] = row[j];
    }
}

// ---------- xs = x * dis[node] (prescale: keeps per-edge gather dependency-free) ----------
__global__ void k_xs(const float* __restrict__ x, const float* __restrict__ dis,
                     float* __restrict__ xs, int n16) {
    int i = blockIdx.x * blockDim.x + threadIdx.x;
    if (i >= n16) return;
    float d = dis[i >> 4];  // 16 float4s per node (64 feats)
    float4 v = ((const float4*)x)[i];
    v.x *= d; v.y *= d; v.z *= d; v.w *= d;
    ((float4*)xs)[i] = v;
}

// ---------- fused: gather1 + GEMM1 + bias + relu + W2 projection ----------
// one wave per node; 4 edge slots x 16 lanes x float4; unroll x4 => 16 rows in flight
// epilogue: h (128) kept in regs (h0,h1 per lane), dot with W2 via butterfly reduce,
// writes padded 16-float h2p row. No block barrier (wave-local LDS sync only).
__global__ __launch_bounds__(256) void k_l1(const float* __restrict__ xs,
                                            const int* __restrict__ src,
                                            const int* __restrict__ rowptr,
                                            const float* __restrict__ dis,
                                            const float* __restrict__ W1,
                                            const float* __restrict__ b1,
                                            const float* __restrict__ W2,
                                            float* __restrict__ h2p, int n) {
    __shared__ float hacc[4][64];
    int w = threadIdx.x >> 6, lane = threadIdx.x & 63;
    int q = lane >> 4;   // edge slot 0..3
    int f4 = lane & 15;  // float4 chunk within 64-float row
    int i = blockIdx.x * 4 + w;
    if (i >= n) return;  // wave-uniform; no block barriers below => safe

    float d = dis[i];
    float4 acc = make_float4(0.f, 0.f, 0.f, 0.f);
    if (q == 0)  // self-loop term (xs already carries d_i)
        acc = ((const float4*)(xs + (size_t)i * IN_F))[f4];
    int end = rowptr[i + 1];
    int e = rowptr[i] + q;
    for (; e + 12 < end; e += 16) {
        int s0 = src[e], s1 = src[e + 4], s2 = src[e + 8], s3 = src[e + 12];
        float4 v0 = ((const float4*)(xs + (size_t)s0 * IN_F))[f4];
        float4 v1 = ((const float4*)(xs + (size_t)s1 * IN_F))[f4];
        float4 v2 = ((const float4*)(xs + (size_t)s2 * IN_F))[f4];
        float4 v3 = ((const float4*)(xs + (size_t)s3 * IN_F))[f4];
        acc.x += (v0.x + v1.x) + (v2.x + v3.x);
        acc.y += (v0.y + v1.y) + (v2.y + v3.y);
        acc.z += (v0.z + v1.z) + (v2.z + v3.z);
        acc.w += (v0.w + v1.w) + (v2.w + v3.w);
    }
    for (; e + 4 < end; e += 8) {
        int s0 = src[e], s1 = src[e + 4];
        float4 v0 = ((const float4*)(xs + (size_t)s0 * IN_F))[f4];
        float4 v1 = ((const float4*)(xs + (size_t)s1 * IN_F))[f4];
        acc.x += v0.x + v1.x;
        acc.y += v0.y + v1.y;
        acc.z += v0.z + v1.z;
        acc.w += v0.w + v1.w;
    }
    if (e < end) {
        int s0 = src[e];
        float4 v0 = ((const float4*)(xs + (size_t)s0 * IN_F))[f4];
        acc.x += v0.x;
        acc.y += v0.y;
        acc.z += v0.z;
        acc.w += v0.w;
    }
    // combine the 4 edge slots
    acc.x += __shfl_xor(acc.x, 16); acc.y += __shfl_xor(acc.y, 16);
    acc.z += __shfl_xor(acc.z, 16); acc.w += __shfl_xor(acc.w, 16);
    acc.x += __shfl_xor(acc.x, 32); acc.y += __shfl_xor(acc.y, 32);
    acc.z += __shfl_xor(acc.z, 32); acc.w += __shfl_xor(acc.w, 32);
    if (q == 0) {
        acc.x *= d; acc.y *= d; acc.z *= d; acc.w *= d;
        ((float4*)hacc[w])[f4] = acc;
    }
    // wave-local LDS visibility: writer lanes and readers are the same wave
    asm volatile("s_waitcnt lgkmcnt(0)" ::: "memory");

    float h0 = b1[lane], h1 = b1[lane + 64];
#pragma unroll
    for (int k4 = 0; k4 < 16; ++k4) {
        float4 a = ((const float4*)hacc[w])[k4];  // LDS broadcast
        const float* wp = W1 + (k4 * 4) * HID + lane;
        h0 = fmaf(a.x, wp[0 * HID], h0);      h1 = fmaf(a.x, wp[0 * HID + 64], h1);
        h0 = fmaf(a.y, wp[1 * HID], h0);      h1 = fmaf(a.y, wp[1 * HID + 64], h1);
        h0 = fmaf(a.z, wp[2 * HID], h0);      h1 = fmaf(a.z, wp[2 * HID + 64], h1);
        h0 = fmaf(a.w, wp[3 * HID], h0);      h1 = fmaf(a.w, wp[3 * HID + 64], h1);
    }
    h0 = fmaxf(h0, 0.f);
    h1 = fmaxf(h1, 0.f);

    // W2 projection: lane owns h-features {lane, lane+64}
    const float* w2a = W2 + lane * NCLS;
    const float* w2b = W2 + (lane + 64) * NCLS;
    float p[NCLS];
#pragma unroll
    for (int c = 0; c < NCLS; ++c) p[c] = fmaf(h0, w2a[c], h1 * w2b[c]);
#pragma unroll
    for (int c = 0; c < NCLS; ++c) {
        float v = p[c];
        v += __shfl_xor(v, 1);  v += __shfl_xor(v, 2);  v += __shfl_xor(v, 4);
        v += __shfl_xor(v, 8);  v += __shfl_xor(v, 16); v += __shfl_xor(v, 32);
        p[c] = v;
    }
    if (lane < 4) {  // padded 16-float row (zeros in 10..15); compile-time p indices
        float4* o = (float4*)(h2p + (size_t)i * 16);
        if (lane == 0)      o[0] = make_float4(d * p[0], d * p[1], d * p[2], d * p[3]);
        else if (lane == 1) o[1] = make_float4(d * p[4], d * p[5], d * p[6], d * p[7]);
        else if (lane == 2) o[2] = make_float4(d * p[8], d * p[9], 0.f, 0.f);
        else                o[3] = make_float4(0.f, 0.f, 0.f, 0.f);
    }
}

// ---------- fused gather2 + b2 + log-softmax + per-block partial reduce ----------
// wave per node (grid-stride); 4 slots x 16 lanes; rows are padded 64B => coalesced
__global__ __launch_bounds__(256) void k_lsm2(const float* __restrict__ h2p,
                                              const int* __restrict__ src,
                                              const int* __restrict__ rowptr,
                                              const float* __restrict__ dis,
                                              const float* __restrict__ b2,
                                              float* __restrict__ partial, int n) {
    __shared__ float sred[4][16];
    int w = threadIdx.x >> 6, lane = threadIdx.x & 63;
    int q = lane >> 4, c = lane & 15;
    int gw = blockIdx.x * 4 + w;
    int nw = gridDim.x * 4;
    float b2c = (c < NCLS) ? b2[c] : 0.f;
    float bsum = 0.f;
    for (int i = gw; i < n; i += nw) {
        int beg = rowptr[i], end = rowptr[i + 1];
        float acc = (q == 0) ? h2p[(size_t)i * 16 + c] : 0.f;  // self
        int e = beg + q;
        for (; e + 12 < end; e += 16) {
            int s0 = src[e], s1 = src[e + 4], s2 = src[e + 8], s3 = src[e + 12];
            float v0 = h2p[(size_t)s0 * 16 + c];
            float v1 = h2p[(size_t)s1 * 16 + c];
            float v2 = h2p[(size_t)s2 * 16 + c];
            float v3 = h2p[(size_t)s3 * 16 + c];
            acc += (v0 + v1) + (v2 + v3);
        }
        for (; e + 4 < end; e += 8) {
            int s0 = src[e], s1 = src[e + 4];
            acc += h2p[(size_t)s0 * 16 + c] + h2p[(size_t)s1 * 16 + c];
        }
        if (e < end) acc += h2p[(size_t)src[e] * 16 + c];
        // combine slots (all lanes end with the full sum)
        acc += __shfl_xor(acc, 16);
        acc += __shfl_xor(acc, 32);
        float vv = b2c + dis[i] * acc;
        // softmax over c=0..9 within each 16-lane group
        float m = (c < NCLS) ? vv : -1e30f;
        m = fmaxf(m, __shfl_xor(m, 1));
        m = fmaxf(m, __shfl_xor(m, 2));
        m = fmaxf(m, __shfl_xor(m, 4));
        m = fmaxf(m, __shfl_xor(m, 8));
        float ex = (c < NCLS) ? __expf(vv - m) : 0.f;
        float se = ex;
        se += __shfl_xor(se, 1);
        se += __shfl_xor(se, 2);
        se += __shfl_xor(se, 4);
        se += __shfl_xor(se, 8);
        float lse = m + __logf(se);
        if (q == 0 && c < NCLS) bsum += vv - lse;
    }
    if (q == 0) sred[w][c] = bsum;  // c>=10 lanes wrote 0
    __syncthreads();
    if (threadIdx.x < 16) {
        float t = sred[0][threadIdx.x] + sred[1][threadIdx.x] +
                  sred[2][threadIdx.x] + sred[3][threadIdx.x];
        partial[blockIdx.x * 16 + threadIdx.x] = t;
    }
}

// ---------- final reduction of per-block partials ----------
__global__ void k_final(const float* __restrict__ partial, float* __restrict__ out,
                        int nb16, float inv_n) {
    __shared__ float sred[256];
    float s = 0.f;
    for (int j = threadIdx.x; j < nb16; j += 256) s += partial[j];  // j&15 constant per thread
    sred[threadIdx.x] = s;
    __syncthreads();
    if (threadIdx.x < 16) {
        float t = 0.f;
        for (int r = threadIdx.x; r < 256; r += 16) t += sred[r];
        if (threadIdx.x < NCLS) out[threadIdx.x] = t * inv_n;
    }
}

extern "C" void kernel_launch(void* const* d_in, const int* in_sizes, int n_in,
                              void* d_out, int out_size, void* d_ws, size_t ws_size,
                              hipStream_t stream) {
    const float* x = (const float*)d_in[0];
    const int* eidx = (const int*)d_in[1];
    const float* W1 = (const float*)d_in[2];
    const float* b1 = (const float*)d_in[3];
    const float* W2 = (const float*)d_in[4];
    const float* b2 = (const float*)d_in[5];
    float* out = (float*)d_out;

    const int N = in_sizes[0] / IN_F;  // 100000
    const int E = in_sizes[1] / 2;     // 1600000
    const int* row = eidx;             // sources
    const int* col = eidx + E;         // targets

    const int NB = (N + 255) / 256;  // scan blocks (391 <= 512)

    // workspace layout (4-byte words, 1024-word aligned)
    size_t o = 0;
    auto alloc = [&](size_t words) {
        size_t r = o;
        o += (words + 1023) & ~(size_t)1023;
        return r;
    };
    float* ws = (float*)d_ws;
    float* dis = ws + alloc(N);
    float* xs = ws + alloc((size_t)N * IN_F);
    float* h2p = ws + alloc((size_t)N * 16);
    float* partial = ws + alloc(LSM_BLOCKS * 16);
    int* src = (int*)(ws + alloc(E));
    int* rowptr = (int*)(ws + alloc(N + 1));
    int* cnt = (int*)(ws + alloc(N));
    int* pos = (int*)(ws + alloc(N));
    int* bsum = (int*)(ws + alloc(1024));
    int* boff = (int*)(ws + alloc(1024));

    const int B = 256;
    const int E4 = (E + 3) / 4;

    // ---- CSR build + degrees (dis, pos fused into scan) ----
    k_zero_int<<<(N + B - 1) / B, B, 0, stream>>>(cnt, N);
    k_hist<<<(E4 + B - 1) / B, B, 0, stream>>>(col, cnt, E);
    k_blocksum<<<NB, 256, 0, stream>>>(cnt, bsum, N);
    k_scan_bsum<<<1, 512, 0, stream>>>(bsum, boff, NB, rowptr, N, E);
    k_scan_final<<<NB, 256, 0, stream>>>(cnt, boff, rowptr, pos, dis, N);
    k_fill<<<(E4 + B - 1) / B, B, 0, stream>>>(row, col, pos, src, E);

    // ---- prescale + layer 1 + relu + W2 projection ----
    k_xs<<<(N * 16 + B - 1) / B, B, 0, stream>>>(x, dis, xs, N * 16);
    k_l1<<<(N + 3) / 4, 256, 0, stream>>>(xs, src, rowptr, dis, W1, b1, W2, h2p, N);

    // ---- layer 2 aggregate + log-softmax + partial reduce ----
    k_lsm2<<<LSM_BLOCKS, 256, 0, stream>>>(h2p, src, rowptr, dis, b2, partial, N);
    k_final<<<1, 256, 0, stream>>>(partial, out, LSM_BLOCKS * 16, 1.0f / (float)N);
}